// Round 15
// baseline (260.210 us; speedup 1.0000x reference)
//
#include <hip/hip_runtime.h>
#include <hip/hip_bf16.h>

// ---------------- problem constants (match setup_inputs) ----------------
#define T_TOK 4096
#define H_DIM 1024
#define E_NUM 8
#define I_DIM 3584
#define NPAIR (T_TOK * 2)   // top_k = 2
#define MAX_RT 72           // worst-case total row tiles: sum ceil(cnt_e/128) <= 64+7

#define BM 128
#define BN 128
#define BK 64

typedef __attribute__((ext_vector_type(8))) short bf16x8;
typedef __attribute__((ext_vector_type(4))) float f32x4;
typedef __attribute__((ext_vector_type(8))) unsigned short ushort8_t;
typedef __attribute__((ext_vector_type(4))) unsigned short ushort4_t;

// RNE fp32 -> bf16
__device__ __forceinline__ unsigned short f2bf(float x) {
  unsigned int u = __float_as_uint(x);
  unsigned int r = (u + 0x7FFFu + ((u >> 16) & 1u)) >> 16;
  return (unsigned short)r;
}

// async 16B global -> LDS (dest: wave-uniform base, HW adds lane*16)
__device__ __forceinline__ void gload16(const void* g, unsigned short* l) {
  __builtin_amdgcn_global_load_lds(
      (const __attribute__((address_space(1))) void*)g,
      (__attribute__((address_space(3))) void*)l, 16, 0, 0);
}

// ---------------- fused prep: router (global gw) + 2-tile transposes -------
// smem = 16.7 KB -> 8 blocks/CU (was 33 KB / 4 blocks: router LDS tax removed)
__device__ __forceinline__ void transpose_body(const float* __restrict__ src,
                                               unsigned short* __restrict__ dst,
                                               int R, int C, int e, int c0, int r0,
                                               float (*tile)[65]) {
  const float* s = src + (size_t)e * R * C;
  unsigned short* d = dst + (size_t)e * R * C;
  const int th = threadIdx.x;
  const int tr = th >> 4;
  const int tc4 = (th & 15) * 4;
#pragma unroll
  for (int it = 0; it < 4; ++it) {
    const int r = it * 16 + tr;
    float4 v = *reinterpret_cast<const float4*>(s + (size_t)(r0 + r) * C + c0 + tc4);
    tile[r][tc4] = v.x; tile[r][tc4 + 1] = v.y; tile[r][tc4 + 2] = v.z; tile[r][tc4 + 3] = v.w;
  }
  __syncthreads();
  const int wc = th >> 3;
  const int wr = (th & 7) * 8;
#pragma unroll
  for (int it = 0; it < 2; ++it) {
    const int c = it * 32 + wc;
    ushort8_t o;
#pragma unroll
    for (int j = 0; j < 8; ++j) o[j] = f2bf(tile[wr + j][c]);
    *reinterpret_cast<ushort8_t*>(d + (size_t)(c0 + c) * R + r0 + wr) = o;
  }
}

__device__ __forceinline__ void router_body(const float* __restrict__ hs,
                                            const float* __restrict__ gw,
                                            unsigned short* __restrict__ hsb,
                                            int* __restrict__ eid, float* __restrict__ wgt,
                                            int* __restrict__ counts, int rbid,
                                            int* s_cnt) {
  const int th = threadIdx.x;
  if (th < E_NUM) s_cnt[th] = 0;
  __syncthreads();
  const int l = th & 63, w = th >> 6;
#pragma unroll 1
  for (int tt = 0; tt < 4; ++tt) {
    const int t = rbid * 16 + w * 4 + tt;
    const float* hrow = hs + (size_t)t * H_DIM;
    unsigned short* brow = hsb + (size_t)t * H_DIM;
    float acc[E_NUM];
#pragma unroll
    for (int e = 0; e < E_NUM; ++e) acc[e] = 0.f;
#pragma unroll
    for (int i = 0; i < 4; ++i) {
      const int h0 = i * 256 + l * 4;
      const f32x4 x = *reinterpret_cast<const f32x4*>(hrow + h0);
      ushort4_t o = { f2bf(x[0]), f2bf(x[1]), f2bf(x[2]), f2bf(x[3]) };
      *reinterpret_cast<ushort4_t*>(brow + h0) = o;
#pragma unroll
      for (int j = 0; j < 4; ++j) {
        const int h = h0 + j;
        // gw is 32 KB: L1/L2-resident; lanes stride 32B -> coalesced
        const f32x4 g0 = *reinterpret_cast<const f32x4*>(gw + h * 8);
        const f32x4 g1 = *reinterpret_cast<const f32x4*>(gw + h * 8 + 4);
        acc[0] += x[j] * g0[0]; acc[1] += x[j] * g0[1];
        acc[2] += x[j] * g0[2]; acc[3] += x[j] * g0[3];
        acc[4] += x[j] * g1[0]; acc[5] += x[j] * g1[1];
        acc[6] += x[j] * g1[2]; acc[7] += x[j] * g1[3];
      }
    }
#pragma unroll
    for (int e = 0; e < E_NUM; ++e) {
#pragma unroll
      for (int off = 1; off < 64; off <<= 1) acc[e] += __shfl_xor(acc[e], off);
    }
    if (l == 0) {
      int i1 = 0;
#pragma unroll
      for (int e = 1; e < E_NUM; ++e) if (acc[e] > acc[i1]) i1 = e;
      int i2 = (i1 == 0) ? 1 : 0;
#pragma unroll
      for (int e = 0; e < E_NUM; ++e) if (e != i1 && acc[e] > acc[i2]) i2 = e;
      const float e2 = __expf(acc[i2] - acc[i1]);
      const float inv = 1.f / (1.f + e2);
      eid[t * 2] = i1;     wgt[t * 2] = inv;
      eid[t * 2 + 1] = i2; wgt[t * 2 + 1] = e2 * inv;
      atomicAdd(&s_cnt[i1], 1);
      atomicAdd(&s_cnt[i2], 1);
    }
  }
  __syncthreads();
  if (th < E_NUM && s_cnt[th] > 0) atomicAdd(&counts[th], s_cnt[th]);
}

// grid 7424: [0,256) router | [256,3840) w1 (2 tiles each) | [3840,7424) w2
__global__ __launch_bounds__(256) void prep_kernel(
    const float* __restrict__ w1, const float* __restrict__ w2,
    const float* __restrict__ hs, const float* __restrict__ gw,
    unsigned short* __restrict__ w1t, unsigned short* __restrict__ w2t,
    unsigned short* __restrict__ hsb,
    int* __restrict__ eid, float* __restrict__ wgt, int* __restrict__ counts) {
  __shared__ float tile[64][65];
  __shared__ int s_cnt[E_NUM];
  const int bid = blockIdx.x;
  if (bid < 256) {
    router_body(hs, gw, hsb, eid, wgt, counts, bid, s_cnt);
    return;
  }
  const int idx = bid - 256;
  const float* src;
  unsigned short* dst;
  int R, C, e, c0, r0;
  if (idx < 3584) {             // w1: R=1024, C=3584; 56c x 8 row-pairs per e
    e = idx / 448; const int rem = idx % 448;
    R = H_DIM; C = I_DIM; c0 = (rem % 56) * 64; r0 = (rem / 56) * 128;
    src = w1; dst = w1t;
  } else {                      // w2: R=3584, C=1024; 16c x 28 row-pairs per e
    const int i2 = idx - 3584;
    e = i2 / 448; const int rem = i2 % 448;
    R = I_DIM; C = H_DIM; c0 = (rem % 16) * 64; r0 = (rem / 16) * 128;
    src = w2; dst = w2t;
  }
  transpose_body(src, dst, R, C, e, c0, r0, tile);
  __syncthreads();
  transpose_body(src, dst, R, C, e, c0, r0 + 64, tile);
}

// ---------------- scatter: block-local histogram + range reservation -------
__global__ void scatter_kernel(const int* __restrict__ eid, const int* __restrict__ counts,
                               int* __restrict__ fill, int* __restrict__ rowmap,
                               int* __restrict__ posmap) {
  __shared__ int hist[E_NUM], base[E_NUM];
  const int th = threadIdx.x;
  const int p = blockIdx.x * 256 + th;
  if (th < E_NUM) hist[th] = 0;
  __syncthreads();
  const int e = eid[p];
  const int rloc = atomicAdd(&hist[e], 1);
  __syncthreads();
  if (th < E_NUM) base[th] = (hist[th] > 0) ? atomicAdd(&fill[th], hist[th]) : 0;
  __syncthreads();
  int off = 0;
#pragma unroll
  for (int i = 0; i < E_NUM; ++i) off += (i < e) ? counts[i] : 0;
  const int pos = off + base[e] + rloc;
  rowmap[pos] = p;
  posmap[p] = pos;
}

// ------ combine: out[t] = sum over {ks,pair} of res[ks][pos] (fixed order) --
__global__ void combine_kernel(const float* __restrict__ res, const int* __restrict__ posmap,
                               float* __restrict__ out) {
  const int t = blockIdx.x;
  const int th = threadIdx.x;
  const size_t a = (size_t)posmap[t * 2] * H_DIM + th * 4;
  const size_t b = (size_t)posmap[t * 2 + 1] * H_DIM + th * 4;
  const size_t S = (size_t)NPAIR * H_DIM;
  const float4 a0 = *reinterpret_cast<const float4*>(res + a);
  const float4 b0 = *reinterpret_cast<const float4*>(res + b);
  const float4 a1 = *reinterpret_cast<const float4*>(res + S + a);
  const float4 b1 = *reinterpret_cast<const float4*>(res + S + b);
  float4 o = { ((a0.x + a1.x) + (b0.x + b1.x)), ((a0.y + a1.y) + (b0.y + b1.y)),
               ((a0.z + a1.z) + (b0.z + b1.z)), ((a0.w + a1.w) + (b0.w + b1.w)) };
  *reinterpret_cast<float4*>(out + (size_t)t * H_DIM + th * 4) = o;
}

// ---------------- grouped GEMM (128x128 tile, 2x2 waves of 64x64, occ 4) ---
// MODE 0: supertiled XCD chunks (9rt x 4ct); silu -> act bf16
// MODE 1: K-split 2 (ks slow) + band-of-2rt chunks; res[ks] plain stores
template <int MODE, int NCT, int KS>
__launch_bounds__(256, 4)
__global__ void moe_gemm(const unsigned short* __restrict__ hsb,
                         const unsigned short* __restrict__ wt,
                         const unsigned short* __restrict__ act_in,
                         unsigned short* __restrict__ act_out,
                         float* __restrict__ res,
                         const int* __restrict__ counts,
                         const int* __restrict__ rowmap,
                         const float* __restrict__ wgt) {
  constexpr int KROW = (MODE == 0) ? H_DIM : I_DIM;   // A/B row stride
  constexpr int KD = KROW / KS;                        // K extent per block
  constexpr int NWG = MAX_RT * NCT * KS;               // 2016 / 1152, %8==0
  constexpr int CHUNK = NWG / 8;                       // 252 / 144

  __shared__ unsigned short As[BM * BK];
  __shared__ unsigned short Bs[BN * BK];
  __shared__ float s_w[BM];

  // T1 bijective XCD swizzle
  const int bid = blockIdx.x;
  const int wgid = (bid & 7) * CHUNK + (bid >> 3);
  int rt, ct, ksi = 0;
  if (MODE == 0) {
    // supertile 9rt x 4ct within each 252-wgid chunk: A 2.3MB + B 1MB in L2
    const int l = wgid % CHUNK;
    const int sg = l / 36;
    const int q = l % 36;
    rt = (wgid / CHUNK) * 9 + q % 9;
    ct = sg * 4 + q / 9;
  } else {
    // chunk = 144: ks slow (72 each); band of 2rt x 8ct within each half
    const int c9 = (wgid / CHUNK) * 9;
    int l = wgid % CHUNK;
    ksi = l / (CHUNK / KS);
    l %= (CHUNK / KS);
    if (l < 64) {
      const int band = l >> 4, inner = l & 15;
      rt = c9 + band * 2 + (inner & 1);
      ct = inner >> 1;
    } else {
      rt = c9 + 8;
      ct = l - 64;
    }
  }
  const int kbase = ksi * KD;

  // expert walk from counts (prefix on the fly)
  int e = -1, loc_rt = 0, off_e = 0, cnt = 0;
  {
    int acc_t = 0, off = 0;
#pragma unroll
    for (int ee = 0; ee < E_NUM; ++ee) {
      const int c = counts[ee];
      const int nt = (c + BM - 1) >> 7;
      if (e < 0 && rt < acc_t + nt) { e = ee; loc_rt = rt - acc_t; off_e = off; cnt = c; }
      acc_t += nt; off += c;
    }
  }
  if (e < 0) return;

  const int cnt_local = min(BM, cnt - loc_rt * BM);
  const int r_base = off_e + loc_rt * BM;
  const int th = threadIdx.x;
  const int lane = th & 63, wid = th >> 6;

  if (MODE == 1 && th < BM) {
    int r = loc_rt * BM + th;
    if (r >= cnt) r = cnt - 1;
    s_w[th] = wgt[rowmap[off_e + r]];
  }

  const int n0 = ct * BN;
  const unsigned short* wbase =
      wt + (size_t)e * ((size_t)I_DIM * H_DIM) + (size_t)n0 * KROW + kbase;

  // staging geometry: lane covers (row-group + lane/8, chunk = lane%8)
  // LDS dest linear; source chunk pre-swizzled: cg = (lane&7) ^ (row&7)
  const int srow = lane >> 3;
  const int cg = (lane & 7) ^ srow;
  const char* aptr[4];
  const char* bptr[4];
#pragma unroll
  for (int i = 0; i < 4; ++i) {
    const int r = i * 32 + wid * 8 + srow;
    const int rr = (r < cnt_local) ? r : (cnt_local - 1);
    if (MODE == 0) {
      const int tok = rowmap[off_e + loc_rt * BM + rr] >> 1;
      aptr[i] = (const char*)(hsb + (size_t)tok * H_DIM) + cg * 16;
    } else {
      aptr[i] = (const char*)(act_in + (size_t)(r_base + rr) * I_DIM + kbase) + cg * 16;
    }
    bptr[i] = (const char*)(wbase + (size_t)r * KROW) + cg * 16;
  }
  unsigned short* dstA[4];
  unsigned short* dstB[4];
#pragma unroll
  for (int i = 0; i < 4; ++i) {
    dstA[i] = &As[(i * 32 + wid * 8) * BK];   // wave-uniform
    dstB[i] = &Bs[(i * 32 + wid * 8) * BK];
  }

  f32x4 acc[4][4];
#pragma unroll
  for (int m = 0; m < 4; ++m)
#pragma unroll
    for (int n = 0; n < 4; ++n) acc[m][n] = (f32x4){0.f, 0.f, 0.f, 0.f};

  const int wm = (wid >> 1) * 64;
  const int wn = (wid & 1) * 64;
  const int fr = lane & 15;
  const int fq = lane >> 4;
  const int sxor = fr & 7;

  for (int k0 = 0; k0 < KD; k0 += BK) {
    const int kb = k0 * 2;
#pragma unroll
    for (int i = 0; i < 4; ++i) gload16(aptr[i] + kb, dstA[i]);
#pragma unroll
    for (int i = 0; i < 4; ++i) gload16(bptr[i] + kb, dstB[i]);
    __syncthreads();   // drains vmcnt before s_barrier

#pragma unroll
    for (int kk = 0; kk < 2; ++kk) {
      bf16x8 af[4], bf[4];
#pragma unroll
      for (int m = 0; m < 4; ++m)
        af[m] = *reinterpret_cast<const bf16x8*>(
            &As[(wm + m * 16 + fr) * BK + ((kk * 4 + fq) ^ sxor) * 8]);
#pragma unroll
      for (int n = 0; n < 4; ++n)
        bf[n] = *reinterpret_cast<const bf16x8*>(
            &Bs[(wn + n * 16 + fr) * BK + ((kk * 4 + fq) ^ sxor) * 8]);
#pragma unroll
      for (int m = 0; m < 4; ++m)
#pragma unroll
        for (int n = 0; n < 4; ++n)
          acc[m][n] = __builtin_amdgcn_mfma_f32_16x16x32_bf16(af[m], bf[n], acc[m][n], 0, 0, 0);
    }
    __syncthreads();
  }

  // ---- epilogue ----
#pragma unroll
  for (int m = 0; m < 4; ++m) {
    const int row = wm + m * 16 + fq * 4;
#pragma unroll
    for (int n = 0; n < 4; ++n) {
      const int col = wn + n * 16 + fr;
#pragma unroll
      for (int r = 0; r < 4; ++r) {
        const int rw = row + r;
        if (rw < cnt_local) {
          const float x = acc[m][n][r];
          if (MODE == 0) {
            const float s = x / (1.f + __expf(-x));   // silu
            act_out[(size_t)(r_base + rw) * I_DIM + n0 + col] = f2bf(s);
          } else {
            res[(size_t)ksi * ((size_t)NPAIR * H_DIM) +
                (size_t)(r_base + rw) * H_DIM + n0 + col] = x * s_w[rw];
          }
        }
      }
    }
  }
}

// ---------------- launch ----------------
extern "C" void kernel_launch(void* const* d_in, const int* in_sizes, int n_in,
                              void* d_out, int out_size, void* d_ws, size_t ws_size,
                              hipStream_t stream) {
  const float* hs = (const float*)d_in[0];
  const float* gw = (const float*)d_in[1];
  const float* w1 = (const float*)d_in[2];
  const float* w2 = (const float*)d_in[3];
  float* out = (float*)d_out;

  char* ws = (char*)d_ws;
  const size_t WMAT = (size_t)E_NUM * I_DIM * H_DIM * 2;   // 58,720,256 B
  // layout: [w2t][act][w1t][hsb][small] so (w1t+hsb) = 67.1MB contiguous dead
  // region after gemm0 -> res[2][NPAIR][H] fp32 (exactly 67,108,864 B) fits.
  unsigned short* w2t = (unsigned short*)ws;                // [E][H][I] bf16
  unsigned short* act = (unsigned short*)(ws + WMAT);       // [NPAIR][I] bf16
  unsigned short* w1t = (unsigned short*)(ws + 2 * WMAT);   // [E][I][H] bf16
  unsigned short* hsb = (unsigned short*)(ws + 3 * WMAT);   // [T][H] bf16
  float* res = (float*)w1t;                                 // [2][NPAIR][H] fp32
  char* small = ws + 3 * WMAT + (size_t)T_TOK * H_DIM * 2;
  int* eid = (int*)small;                          // NPAIR
  float* wgt = (float*)(small + NPAIR * 4);        // NPAIR
  int* rowmap = (int*)(small + 2 * NPAIR * 4);     // NPAIR
  int* posmap = (int*)(small + 3 * NPAIR * 4);     // NPAIR
  int* counts = (int*)(small + 4 * NPAIR * 4);     // 8
  int* fill = counts + 8;                          // 8

  hipMemsetAsync(counts, 0, 16 * sizeof(int), stream);

  prep_kernel<<<7424, 256, 0, stream>>>(w1, w2, hs, gw, w1t, w2t, hsb, eid, wgt, counts);
  scatter_kernel<<<NPAIR / 256, 256, 0, stream>>>(eid, counts, fill, rowmap, posmap);

  moe_gemm<0, I_DIM / BN, 1><<<MAX_RT * (I_DIM / BN), 256, 0, stream>>>(
      hsb, w1t, nullptr, act, nullptr, counts, rowmap, wgt);
  moe_gemm<1, H_DIM / BN, 2><<<MAX_RT * (H_DIM / BN) * 2, 256, 0, stream>>>(
      hsb, w2t, act, nullptr, res, counts, rowmap, wgt);

  combine_kernel<<<T_TOK, 256, 0, stream>>>(res, posmap, out);
}

// Round 16
// 251.262 us; speedup vs baseline: 1.0356x; 1.0356x over previous
//
#include <hip/hip_runtime.h>
#include <hip/hip_bf16.h>

// ---------------- problem constants (match setup_inputs) ----------------
#define T_TOK 4096
#define H_DIM 1024
#define E_NUM 8
#define I_DIM 3584
#define NPAIR (T_TOK * 2)   // top_k = 2
#define MAX_RT 72           // worst-case total row tiles: sum ceil(cnt_e/128) <= 64+7

#define BM 128
#define BN 128
#define BK 64

typedef __attribute__((ext_vector_type(8))) short bf16x8;
typedef __attribute__((ext_vector_type(4))) float f32x4;
typedef __attribute__((ext_vector_type(8))) unsigned short ushort8_t;
typedef __attribute__((ext_vector_type(4))) unsigned short ushort4_t;

// RNE fp32 -> bf16
__device__ __forceinline__ unsigned short f2bf(float x) {
  unsigned int u = __float_as_uint(x);
  unsigned int r = (u + 0x7FFFu + ((u >> 16) & 1u)) >> 16;
  return (unsigned short)r;
}

// async 16B global -> LDS (dest: wave-uniform base, HW adds lane*16)
__device__ __forceinline__ void gload16(const void* g, unsigned short* l) {
  __builtin_amdgcn_global_load_lds(
      (const __attribute__((address_space(1))) void*)g,
      (__attribute__((address_space(3))) void*)l, 16, 0, 0);
}

// ---------------- fused prep: router (first) + dual-tile transposes -------
// dual tile: two 64-row passes share LDS; writes fused -> 256B/row segments
__device__ __forceinline__ void transpose_body2(const float* __restrict__ src,
                                                unsigned short* __restrict__ dst,
                                                int R, int C, int e, int c0, int r0,
                                                char* smem) {
  float (*tile)[65] = reinterpret_cast<float (*)[65]>(smem);
  const float* s = src + (size_t)e * R * C;
  unsigned short* d = dst + (size_t)e * R * C;
  const int th = threadIdx.x;
  const int tr = th >> 4;
  const int tc4 = (th & 15) * 4;
  const int wc = th >> 3;
  const int wr = (th & 7) * 8;
  ushort8_t oA[2];
  // ---- pass A: src rows [r0, r0+64) -> results held in registers
#pragma unroll
  for (int it = 0; it < 4; ++it) {
    const int r = it * 16 + tr;
    float4 v = *reinterpret_cast<const float4*>(s + (size_t)(r0 + r) * C + c0 + tc4);
    tile[r][tc4] = v.x; tile[r][tc4 + 1] = v.y; tile[r][tc4 + 2] = v.z; tile[r][tc4 + 3] = v.w;
  }
  __syncthreads();
#pragma unroll
  for (int it = 0; it < 2; ++it) {
    const int c = it * 32 + wc;
#pragma unroll
    for (int j = 0; j < 8; ++j) oA[it][j] = f2bf(tile[wr + j][c]);
  }
  __syncthreads();   // all reads of pass A done before restage
  // ---- pass B: src rows [r0+64, r0+128); write A+B adjacent (256B/row)
#pragma unroll
  for (int it = 0; it < 4; ++it) {
    const int r = it * 16 + tr;
    float4 v = *reinterpret_cast<const float4*>(s + (size_t)(r0 + 64 + r) * C + c0 + tc4);
    tile[r][tc4] = v.x; tile[r][tc4 + 1] = v.y; tile[r][tc4 + 2] = v.z; tile[r][tc4 + 3] = v.w;
  }
  __syncthreads();
#pragma unroll
  for (int it = 0; it < 2; ++it) {
    const int c = it * 32 + wc;
    ushort8_t oB;
#pragma unroll
    for (int j = 0; j < 8; ++j) oB[j] = f2bf(tile[wr + j][c]);
    *reinterpret_cast<ushort8_t*>(d + (size_t)(c0 + c) * R + r0 + wr) = oA[it];
    *reinterpret_cast<ushort8_t*>(d + (size_t)(c0 + c) * R + r0 + 64 + wr) = oB;
  }
}

__device__ __forceinline__ void router_body(const float* __restrict__ hs,
                                            const float* __restrict__ gw,
                                            unsigned short* __restrict__ hsb,
                                            int* __restrict__ eid, float* __restrict__ wgt,
                                            int* __restrict__ counts, int rbid, char* smem) {
  float* s_gw = reinterpret_cast<float*>(smem);          // 32 KB
  int* s_cnt = reinterpret_cast<int*>(smem + 32768);     // 32 B
  const int th = threadIdx.x;
  for (int u = th; u < 2048; u += 256) {
    const f32x4 v = *reinterpret_cast<const f32x4*>(gw + u * 4);
    *reinterpret_cast<f32x4*>(&s_gw[(u ^ ((u >> 3) & 7)) * 4]) = v;
  }
  if (th < E_NUM) s_cnt[th] = 0;
  __syncthreads();

  const int l = th & 63, w = th >> 6;
#pragma unroll 1
  for (int tt = 0; tt < 4; ++tt) {
    const int t = rbid * 16 + w * 4 + tt;
    const float* hrow = hs + (size_t)t * H_DIM;
    unsigned short* brow = hsb + (size_t)t * H_DIM;
    float acc[E_NUM];
#pragma unroll
    for (int e = 0; e < E_NUM; ++e) acc[e] = 0.f;
#pragma unroll
    for (int i = 0; i < 4; ++i) {
      const int h0 = i * 256 + l * 4;
      const f32x4 x = *reinterpret_cast<const f32x4*>(hrow + h0);
      ushort4_t o = { f2bf(x[0]), f2bf(x[1]), f2bf(x[2]), f2bf(x[3]) };
      *reinterpret_cast<ushort4_t*>(brow + h0) = o;
#pragma unroll
      for (int j = 0; j < 4; ++j) {
        const int h = h0 + j;
        const int p0 = (h * 2) ^ ((h >> 2) & 7);
        const f32x4 g0 = *reinterpret_cast<const f32x4*>(&s_gw[p0 * 4]);
        const f32x4 g1 = *reinterpret_cast<const f32x4*>(&s_gw[(p0 ^ 1) * 4]);
        acc[0] += x[j] * g0[0]; acc[1] += x[j] * g0[1];
        acc[2] += x[j] * g0[2]; acc[3] += x[j] * g0[3];
        acc[4] += x[j] * g1[0]; acc[5] += x[j] * g1[1];
        acc[6] += x[j] * g1[2]; acc[7] += x[j] * g1[3];
      }
    }
#pragma unroll
    for (int e = 0; e < E_NUM; ++e) {
#pragma unroll
      for (int off = 1; off < 64; off <<= 1) acc[e] += __shfl_xor(acc[e], off);
    }
    if (l == 0) {
      int i1 = 0;
#pragma unroll
      for (int e = 1; e < E_NUM; ++e) if (acc[e] > acc[i1]) i1 = e;
      int i2 = (i1 == 0) ? 1 : 0;
#pragma unroll
      for (int e = 0; e < E_NUM; ++e) if (e != i1 && acc[e] > acc[i2]) i2 = e;
      const float e2 = __expf(acc[i2] - acc[i1]);
      const float inv = 1.f / (1.f + e2);
      eid[t * 2] = i1;     wgt[t * 2] = inv;
      eid[t * 2 + 1] = i2; wgt[t * 2 + 1] = e2 * inv;
      atomicAdd(&s_cnt[i1], 1);
      atomicAdd(&s_cnt[i2], 1);
    }
  }
  __syncthreads();
  if (th < E_NUM && s_cnt[th] > 0) atomicAdd(&counts[th], s_cnt[th]);
}

// grid 7424: [0,256) router | [256,3840) w1 (128-row dual) | [3840,7424) w2
__global__ __launch_bounds__(256) void prep_kernel(
    const float* __restrict__ w1, const float* __restrict__ w2,
    const float* __restrict__ hs, const float* __restrict__ gw,
    unsigned short* __restrict__ w1t, unsigned short* __restrict__ w2t,
    unsigned short* __restrict__ hsb,
    int* __restrict__ eid, float* __restrict__ wgt, int* __restrict__ counts) {
  __shared__ char smem[33024];   // router: 32KB+32B; transpose: 16.6KB
  const int bid = blockIdx.x;
  if (bid < 256) {
    router_body(hs, gw, hsb, eid, wgt, counts, bid, smem);
    return;
  }
  const int idx = bid - 256;
  const float* src;
  unsigned short* dst;
  int R, C, e, c0, r0;
  if (idx < 3584) {             // w1: R=1024, C=3584; 56c x 8 row-pairs per e
    e = idx / 448; const int rem = idx % 448;
    R = H_DIM; C = I_DIM; c0 = (rem % 56) * 64; r0 = (rem / 56) * 128;
    src = w1; dst = w1t;
  } else {                      // w2: R=3584, C=1024; 16c x 28 row-pairs per e
    const int i2 = idx - 3584;
    e = i2 / 448; const int rem = i2 % 448;
    R = I_DIM; C = H_DIM; c0 = (rem % 16) * 64; r0 = (rem / 16) * 128;
    src = w2; dst = w2t;
  }
  transpose_body2(src, dst, R, C, e, c0, r0, smem);
}

// ---------------- scatter: block-local histogram + range reservation -------
__global__ void scatter_kernel(const int* __restrict__ eid, const int* __restrict__ counts,
                               int* __restrict__ fill, int* __restrict__ rowmap,
                               int* __restrict__ posmap) {
  __shared__ int hist[E_NUM], base[E_NUM];
  const int th = threadIdx.x;
  const int p = blockIdx.x * 256 + th;
  if (th < E_NUM) hist[th] = 0;
  __syncthreads();
  const int e = eid[p];
  const int rloc = atomicAdd(&hist[e], 1);
  __syncthreads();
  if (th < E_NUM) base[th] = (hist[th] > 0) ? atomicAdd(&fill[th], hist[th]) : 0;
  __syncthreads();
  int off = 0;
#pragma unroll
  for (int i = 0; i < E_NUM; ++i) off += (i < e) ? counts[i] : 0;
  const int pos = off + base[e] + rloc;
  rowmap[pos] = p;
  posmap[p] = pos;
}

// ---------------- combine: out[t] = res[pos(2t)] + res[pos(2t+1)] ----------
__global__ void combine_kernel(const float* __restrict__ res, const int* __restrict__ posmap,
                               float* __restrict__ out) {
  const int t = blockIdx.x;
  const int th = threadIdx.x;
  const int a = posmap[t * 2];
  const int b = posmap[t * 2 + 1];
  const float4 va = *reinterpret_cast<const float4*>(res + (size_t)a * H_DIM + th * 4);
  const float4 vb = *reinterpret_cast<const float4*>(res + (size_t)b * H_DIM + th * 4);
  float4 o = { va.x + vb.x, va.y + vb.y, va.z + vb.z, va.w + vb.w };
  *reinterpret_cast<float4*>(out + (size_t)t * H_DIM + th * 4) = o;
}

// ---------------- grouped GEMM (128x128 tile, 2x2 waves of 64x64, occ 4) ---
// MODE 0: supertiled XCD chunks (9rt x 4ct: A 2.3MB + B 1MB in L2); silu->act
// MODE 1: band-of-2rt chunks (2rt x 8ct: A 1.8MB + B 1.8MB in L2); res stores
template <int MODE, int NCT>
__launch_bounds__(256, 4)
__global__ void moe_gemm(const unsigned short* __restrict__ hsb,
                         const unsigned short* __restrict__ wt,
                         const unsigned short* __restrict__ act_in,
                         unsigned short* __restrict__ act_out,
                         float* __restrict__ res,
                         const int* __restrict__ counts,
                         const int* __restrict__ rowmap,
                         const float* __restrict__ wgt) {
  constexpr int KD = (MODE == 0) ? H_DIM : I_DIM;
  constexpr int NWG = MAX_RT * NCT;          // 2016 / 576, %8==0
  constexpr int CHUNK = NWG / 8;             // 252 / 72

  __shared__ unsigned short As[BM * BK];
  __shared__ unsigned short Bs[BN * BK];
  __shared__ float s_w[BM];

  // T1 bijective XCD swizzle
  const int bid = blockIdx.x;
  const int wgid = (bid & 7) * CHUNK + (bid >> 3);
  int rt, ct;
  if (MODE == 0) {
    // supertile 9rt x 4ct within each 252-wgid chunk: A 2.3MB + B 1MB in L2
    const int l = wgid % CHUNK;
    const int sg = l / 36;          // ct group 0..6
    const int q = l % 36;
    rt = (wgid / CHUNK) * 9 + q % 9;
    ct = sg * 4 + q / 9;
  } else {
    // band of 2 rt x all 8 ct within each 72-wgid chunk (9rt x 8ct):
    // A window 1.8MB + B window 1.8MB both L2-resident
    const int c9 = (wgid / CHUNK) * 9;
    const int l = wgid % CHUNK;
    if (l < 64) {
      const int band = l >> 4, inner = l & 15;
      rt = c9 + band * 2 + (inner & 1);
      ct = inner >> 1;
    } else {
      rt = c9 + 8;
      ct = l - 64;
    }
  }

  // expert walk from counts (prefix on the fly)
  int e = -1, loc_rt = 0, off_e = 0, cnt = 0;
  {
    int acc_t = 0, off = 0;
#pragma unroll
    for (int ee = 0; ee < E_NUM; ++ee) {
      const int c = counts[ee];
      const int nt = (c + BM - 1) >> 7;
      if (e < 0 && rt < acc_t + nt) { e = ee; loc_rt = rt - acc_t; off_e = off; cnt = c; }
      acc_t += nt; off += c;
    }
  }
  if (e < 0) return;

  const int cnt_local = min(BM, cnt - loc_rt * BM);
  const int r_base = off_e + loc_rt * BM;
  const int th = threadIdx.x;
  const int lane = th & 63, wid = th >> 6;

  if (MODE == 1 && th < BM) {
    int r = loc_rt * BM + th;
    if (r >= cnt) r = cnt - 1;
    s_w[th] = wgt[rowmap[off_e + r]];
  }

  const int n0 = ct * BN;
  const unsigned short* wbase = wt + (size_t)e * ((size_t)I_DIM * H_DIM) + (size_t)n0 * KD;

  // staging geometry: lane covers (row-group + lane/8, chunk = lane%8)
  // LDS dest linear; source chunk pre-swizzled: cg = (lane&7) ^ (row&7)
  const int srow = lane >> 3;
  const int cg = (lane & 7) ^ srow;
  const char* aptr[4];
  const char* bptr[4];
#pragma unroll
  for (int i = 0; i < 4; ++i) {
    const int r = i * 32 + wid * 8 + srow;
    const int rr = (r < cnt_local) ? r : (cnt_local - 1);
    if (MODE == 0) {
      const int tok = rowmap[off_e + loc_rt * BM + rr] >> 1;
      aptr[i] = (const char*)(hsb + (size_t)tok * H_DIM) + cg * 16;
    } else {
      aptr[i] = (const char*)(act_in + (size_t)(r_base + rr) * I_DIM) + cg * 16;
    }
    bptr[i] = (const char*)(wbase + (size_t)r * KD) + cg * 16;
  }
  unsigned short* dstA[4];
  unsigned short* dstB[4];
#pragma unroll
  for (int i = 0; i < 4; ++i) {
    dstA[i] = &As[(i * 32 + wid * 8) * BK];   // wave-uniform
    dstB[i] = &Bs[(i * 32 + wid * 8) * BK];
  }

  f32x4 acc[4][4];
#pragma unroll
  for (int m = 0; m < 4; ++m)
#pragma unroll
    for (int n = 0; n < 4; ++n) acc[m][n] = (f32x4){0.f, 0.f, 0.f, 0.f};

  const int wm = (wid >> 1) * 64;
  const int wn = (wid & 1) * 64;
  const int fr = lane & 15;
  const int fq = lane >> 4;
  const int sxor = fr & 7;

  for (int k0 = 0; k0 < KD; k0 += BK) {
    const int kb = k0 * 2;
#pragma unroll
    for (int i = 0; i < 4; ++i) gload16(aptr[i] + kb, dstA[i]);
#pragma unroll
    for (int i = 0; i < 4; ++i) gload16(bptr[i] + kb, dstB[i]);
    __syncthreads();   // drains vmcnt before s_barrier

#pragma unroll
    for (int kk = 0; kk < 2; ++kk) {
      bf16x8 af[4], bf[4];
#pragma unroll
      for (int m = 0; m < 4; ++m)
        af[m] = *reinterpret_cast<const bf16x8*>(
            &As[(wm + m * 16 + fr) * BK + ((kk * 4 + fq) ^ sxor) * 8]);
#pragma unroll
      for (int n = 0; n < 4; ++n)
        bf[n] = *reinterpret_cast<const bf16x8*>(
            &Bs[(wn + n * 16 + fr) * BK + ((kk * 4 + fq) ^ sxor) * 8]);
#pragma unroll
      for (int m = 0; m < 4; ++m)
#pragma unroll
        for (int n = 0; n < 4; ++n)
          acc[m][n] = __builtin_amdgcn_mfma_f32_16x16x32_bf16(af[m], bf[n], acc[m][n], 0, 0, 0);
    }
    __syncthreads();
  }

  // ---- epilogue ----
#pragma unroll
  for (int m = 0; m < 4; ++m) {
    const int row = wm + m * 16 + fq * 4;
#pragma unroll
    for (int n = 0; n < 4; ++n) {
      const int col = wn + n * 16 + fr;
#pragma unroll
      for (int r = 0; r < 4; ++r) {
        const int rw = row + r;
        if (rw < cnt_local) {
          const float x = acc[m][n][r];
          if (MODE == 0) {
            const float s = x / (1.f + __expf(-x));   // silu
            act_out[(size_t)(r_base + rw) * I_DIM + n0 + col] = f2bf(s);
          } else {
            res[(size_t)(r_base + rw) * H_DIM + n0 + col] = x * s_w[rw];
          }
        }
      }
    }
  }
}

// ---------------- launch ----------------
extern "C" void kernel_launch(void* const* d_in, const int* in_sizes, int n_in,
                              void* d_out, int out_size, void* d_ws, size_t ws_size,
                              hipStream_t stream) {
  const float* hs = (const float*)d_in[0];
  const float* gw = (const float*)d_in[1];
  const float* w1 = (const float*)d_in[2];
  const float* w2 = (const float*)d_in[3];
  float* out = (float*)d_out;

  char* ws = (char*)d_ws;
  const size_t WMAT = (size_t)E_NUM * I_DIM * H_DIM * 2;   // 58,720,256 B
  unsigned short* w1t = (unsigned short*)ws;                // [E][I][H] bf16
  unsigned short* w2t = (unsigned short*)(ws + WMAT);       // [E][H][I] bf16
  unsigned short* act = (unsigned short*)(ws + 2 * WMAT);   // [NPAIR][I] bf16
  unsigned short* hsb = (unsigned short*)(ws + 3 * WMAT);   // [T][H] bf16
  // res aliases w1t: dead after MODE0 completes (stream-ordered, race-free).
  float* res = (float*)w1t;                                 // [NPAIR][H] fp32
  char* small = ws + 3 * WMAT + (size_t)T_TOK * H_DIM * 2;
  int* eid = (int*)small;                          // NPAIR
  float* wgt = (float*)(small + NPAIR * 4);        // NPAIR
  int* rowmap = (int*)(small + 2 * NPAIR * 4);     // NPAIR
  int* posmap = (int*)(small + 3 * NPAIR * 4);     // NPAIR
  int* counts = (int*)(small + 4 * NPAIR * 4);     // 8
  int* fill = counts + 8;                          // 8

  hipMemsetAsync(counts, 0, 16 * sizeof(int), stream);

  prep_kernel<<<7424, 256, 0, stream>>>(w1, w2, hs, gw, w1t, w2t, hsb, eid, wgt, counts);
  scatter_kernel<<<NPAIR / 256, 256, 0, stream>>>(eid, counts, fill, rowmap, posmap);

  moe_gemm<0, I_DIM / BN><<<MAX_RT * (I_DIM / BN), 256, 0, stream>>>(
      hsb, w1t, nullptr, act, nullptr, counts, rowmap, wgt);
  moe_gemm<1, H_DIM / BN><<<MAX_RT * (H_DIM / BN), 256, 0, stream>>>(
      hsb, w2t, act, nullptr, res, counts, rowmap, wgt);

  combine_kernel<<<T_TOK, 256, 0, stream>>>(res, posmap, out);
}

// Round 17
// 244.300 us; speedup vs baseline: 1.0651x; 1.0285x over previous
//
#include <hip/hip_runtime.h>
#include <hip/hip_bf16.h>

// ---------------- problem constants (match setup_inputs) ----------------
#define T_TOK 4096
#define H_DIM 1024
#define E_NUM 8
#define I_DIM 3584
#define NPAIR (T_TOK * 2)   // top_k = 2
#define MAX_RT 72           // worst-case total row tiles: sum ceil(cnt_e/128) <= 64+7

#define BM 128
#define BN 128
#define BK 64
#define G0_NWG (MAX_RT * (I_DIM / BN))   // 2016 gemm0 blocks
#define WT_NB 3584                       // dual-tile transpose blocks per matrix

typedef __attribute__((ext_vector_type(8))) short bf16x8;
typedef __attribute__((ext_vector_type(4))) float f32x4;
typedef __attribute__((ext_vector_type(8))) unsigned short ushort8_t;
typedef __attribute__((ext_vector_type(4))) unsigned short ushort4_t;

// RNE fp32 -> bf16
__device__ __forceinline__ unsigned short f2bf(float x) {
  unsigned int u = __float_as_uint(x);
  unsigned int r = (u + 0x7FFFu + ((u >> 16) & 1u)) >> 16;
  return (unsigned short)r;
}

// async 16B global -> LDS (dest: wave-uniform base, HW adds lane*16)
__device__ __forceinline__ void gload16(const void* g, unsigned short* l) {
  __builtin_amdgcn_global_load_lds(
      (const __attribute__((address_space(1))) void*)g,
      (__attribute__((address_space(3))) void*)l, 16, 0, 0);
}

// ---------------- dual-tile transpose (2x 64-row passes, fused 256B writes) -
__device__ __forceinline__ void transpose_body2(const float* __restrict__ src,
                                                unsigned short* __restrict__ dst,
                                                int R, int C, int e, int c0, int r0,
                                                char* smem) {
  float (*tile)[65] = reinterpret_cast<float (*)[65]>(smem);
  const float* s = src + (size_t)e * R * C;
  unsigned short* d = dst + (size_t)e * R * C;
  const int th = threadIdx.x;
  const int tr = th >> 4;
  const int tc4 = (th & 15) * 4;
  const int wc = th >> 3;
  const int wr = (th & 7) * 8;
  ushort8_t oA[2];
  // ---- pass A: src rows [r0, r0+64) -> results held in registers
#pragma unroll
  for (int it = 0; it < 4; ++it) {
    const int r = it * 16 + tr;
    float4 v = *reinterpret_cast<const float4*>(s + (size_t)(r0 + r) * C + c0 + tc4);
    tile[r][tc4] = v.x; tile[r][tc4 + 1] = v.y; tile[r][tc4 + 2] = v.z; tile[r][tc4 + 3] = v.w;
  }
  __syncthreads();
#pragma unroll
  for (int it = 0; it < 2; ++it) {
    const int c = it * 32 + wc;
#pragma unroll
    for (int j = 0; j < 8; ++j) oA[it][j] = f2bf(tile[wr + j][c]);
  }
  __syncthreads();   // all reads of pass A done before restage
  // ---- pass B: src rows [r0+64, r0+128); write A+B adjacent (256B/row)
#pragma unroll
  for (int it = 0; it < 4; ++it) {
    const int r = it * 16 + tr;
    float4 v = *reinterpret_cast<const float4*>(s + (size_t)(r0 + 64 + r) * C + c0 + tc4);
    tile[r][tc4] = v.x; tile[r][tc4 + 1] = v.y; tile[r][tc4 + 2] = v.z; tile[r][tc4 + 3] = v.w;
  }
  __syncthreads();
#pragma unroll
  for (int it = 0; it < 2; ++it) {
    const int c = it * 32 + wc;
    ushort8_t oB;
#pragma unroll
    for (int j = 0; j < 8; ++j) oB[j] = f2bf(tile[wr + j][c]);
    *reinterpret_cast<ushort8_t*>(d + (size_t)(c0 + c) * R + r0 + wr) = oA[it];
    *reinterpret_cast<ushort8_t*>(d + (size_t)(c0 + c) * R + r0 + 64 + wr) = oB;
  }
}

__device__ __forceinline__ void router_body(const float* __restrict__ hs,
                                            const float* __restrict__ gw,
                                            unsigned short* __restrict__ hsb,
                                            int* __restrict__ eid, float* __restrict__ wgt,
                                            int* __restrict__ counts, int rbid, char* smem) {
  float* s_gw = reinterpret_cast<float*>(smem);          // 32 KB
  int* s_cnt = reinterpret_cast<int*>(smem + 32768);     // 32 B
  const int th = threadIdx.x;
  for (int u = th; u < 2048; u += 256) {
    const f32x4 v = *reinterpret_cast<const f32x4*>(gw + u * 4);
    *reinterpret_cast<f32x4*>(&s_gw[(u ^ ((u >> 3) & 7)) * 4]) = v;
  }
  if (th < E_NUM) s_cnt[th] = 0;
  __syncthreads();

  const int l = th & 63, w = th >> 6;
#pragma unroll 1
  for (int tt = 0; tt < 4; ++tt) {
    const int t = rbid * 16 + w * 4 + tt;
    const float* hrow = hs + (size_t)t * H_DIM;
    unsigned short* brow = hsb + (size_t)t * H_DIM;
    float acc[E_NUM];
#pragma unroll
    for (int e = 0; e < E_NUM; ++e) acc[e] = 0.f;
#pragma unroll
    for (int i = 0; i < 4; ++i) {
      const int h0 = i * 256 + l * 4;
      const f32x4 x = *reinterpret_cast<const f32x4*>(hrow + h0);
      ushort4_t o = { f2bf(x[0]), f2bf(x[1]), f2bf(x[2]), f2bf(x[3]) };
      *reinterpret_cast<ushort4_t*>(brow + h0) = o;
#pragma unroll
      for (int j = 0; j < 4; ++j) {
        const int h = h0 + j;
        const int p0 = (h * 2) ^ ((h >> 2) & 7);
        const f32x4 g0 = *reinterpret_cast<const f32x4*>(&s_gw[p0 * 4]);
        const f32x4 g1 = *reinterpret_cast<const f32x4*>(&s_gw[(p0 ^ 1) * 4]);
        acc[0] += x[j] * g0[0]; acc[1] += x[j] * g0[1];
        acc[2] += x[j] * g0[2]; acc[3] += x[j] * g0[3];
        acc[4] += x[j] * g1[0]; acc[5] += x[j] * g1[1];
        acc[6] += x[j] * g1[2]; acc[7] += x[j] * g1[3];
      }
    }
#pragma unroll
    for (int e = 0; e < E_NUM; ++e) {
#pragma unroll
      for (int off = 1; off < 64; off <<= 1) acc[e] += __shfl_xor(acc[e], off);
    }
    if (l == 0) {
      int i1 = 0;
#pragma unroll
      for (int e = 1; e < E_NUM; ++e) if (acc[e] > acc[i1]) i1 = e;
      int i2 = (i1 == 0) ? 1 : 0;
#pragma unroll
      for (int e = 0; e < E_NUM; ++e) if (e != i1 && acc[e] > acc[i2]) i2 = e;
      const float e2 = __expf(acc[i2] - acc[i1]);
      const float inv = 1.f / (1.f + e2);
      eid[t * 2] = i1;     wgt[t * 2] = inv;
      eid[t * 2 + 1] = i2; wgt[t * 2 + 1] = e2 * inv;
      atomicAdd(&s_cnt[i1], 1);
      atomicAdd(&s_cnt[i2], 1);
    }
  }
  __syncthreads();
  if (th < E_NUM && s_cnt[th] > 0) atomicAdd(&counts[th], s_cnt[th]);
}

// ---- kernel1: router (bids 0..255) + w1 dual-transpose (256..3839) --------
__global__ __launch_bounds__(256) void prep1_kernel(
    const float* __restrict__ w1, const float* __restrict__ hs,
    const float* __restrict__ gw,
    unsigned short* __restrict__ w1t, unsigned short* __restrict__ hsb,
    int* __restrict__ eid, float* __restrict__ wgt, int* __restrict__ counts) {
  __shared__ char smem[33024];   // router: 32KB+32B; transpose: 16.6KB
  const int bid = blockIdx.x;
  if (bid < 256) {
    router_body(hs, gw, hsb, eid, wgt, counts, bid, smem);
    return;
  }
  const int idx = bid - 256;     // w1: R=1024, C=3584; 56c x 8 row-pairs per e
  const int e = idx / 448, rem = idx % 448;
  transpose_body2(w1, w1t, H_DIM, I_DIM, e, (rem % 56) * 64, (rem / 56) * 128, smem);
}

// ---------------- scatter: block-local histogram + range reservation -------
__global__ void scatter_kernel(const int* __restrict__ eid, const int* __restrict__ counts,
                               int* __restrict__ fill, int* __restrict__ rowmap,
                               int* __restrict__ posmap) {
  __shared__ int hist[E_NUM], base[E_NUM];
  const int th = threadIdx.x;
  const int p = blockIdx.x * 256 + th;
  if (th < E_NUM) hist[th] = 0;
  __syncthreads();
  const int e = eid[p];
  const int rloc = atomicAdd(&hist[e], 1);
  __syncthreads();
  if (th < E_NUM) base[th] = (hist[th] > 0) ? atomicAdd(&fill[th], hist[th]) : 0;
  __syncthreads();
  int off = 0;
#pragma unroll
  for (int i = 0; i < E_NUM; ++i) off += (i < e) ? counts[i] : 0;
  const int pos = off + base[e] + rloc;
  rowmap[pos] = p;
  posmap[p] = pos;
}

// ---------------- combine: out[t] = res[pos(2t)] + res[pos(2t+1)] ----------
__global__ void combine_kernel(const float* __restrict__ res, const int* __restrict__ posmap,
                               float* __restrict__ out) {
  const int t = blockIdx.x;
  const int th = threadIdx.x;
  const int a = posmap[t * 2];
  const int b = posmap[t * 2 + 1];
  const float4 va = *reinterpret_cast<const float4*>(res + (size_t)a * H_DIM + th * 4);
  const float4 vb = *reinterpret_cast<const float4*>(res + (size_t)b * H_DIM + th * 4);
  float4 o = { va.x + vb.x, va.y + vb.y, va.z + vb.z, va.w + vb.w };
  *reinterpret_cast<float4*>(out + (size_t)t * H_DIM + th * 4) = o;
}

// ---- kernel2: gemm0 (bids 0..2015, supertiled) + w2 dual-transpose --------
// gemm0 is latency-bound (25% MfmaUtil, 1.4 TB/s): w2t blocks soak idle BW.
__global__ __launch_bounds__(256, 4) void gemm0_w2t_kernel(
    const unsigned short* __restrict__ hsb, const unsigned short* __restrict__ w1t,
    unsigned short* __restrict__ act,
    const float* __restrict__ w2, unsigned short* __restrict__ w2t,
    const int* __restrict__ counts, const int* __restrict__ rowmap) {
  __shared__ char smem[(BM * BK + BN * BK) * 2];   // 32 KB
  const int bid = blockIdx.x;
  if (bid >= G0_NWG) {
    const int idx = bid - G0_NWG;  // w2: R=3584, C=1024; 16c x 28 row-pairs per e
    const int e = idx / 448, rem = idx % 448;
    transpose_body2(w2, w2t, I_DIM, H_DIM, e, (rem % 16) * 64, (rem / 16) * 128, smem);
    return;
  }
  unsigned short* As = reinterpret_cast<unsigned short*>(smem);
  unsigned short* Bs = As + BM * BK;

  // T1 bijective XCD swizzle + 9rt x 4ct supertile (A 2.3MB + B 1MB in L2)
  constexpr int CHUNK = G0_NWG / 8;   // 252
  const int wgid = (bid & 7) * CHUNK + (bid >> 3);
  const int l = wgid % CHUNK;
  const int sg = l / 36;
  const int q = l % 36;
  const int rt = (wgid / CHUNK) * 9 + q % 9;
  const int ct = sg * 4 + q / 9;

  // expert walk from counts (prefix on the fly)
  int e = -1, loc_rt = 0, off_e = 0, cnt = 0;
  {
    int acc_t = 0, off = 0;
#pragma unroll
    for (int ee = 0; ee < E_NUM; ++ee) {
      const int c = counts[ee];
      const int nt = (c + BM - 1) >> 7;
      if (e < 0 && rt < acc_t + nt) { e = ee; loc_rt = rt - acc_t; off_e = off; cnt = c; }
      acc_t += nt; off += c;
    }
  }
  if (e < 0) return;

  const int cnt_local = min(BM, cnt - loc_rt * BM);
  const int r_base = off_e + loc_rt * BM;
  const int th = threadIdx.x;
  const int lane = th & 63, wid = th >> 6;

  const int n0 = ct * BN;
  const unsigned short* wbase = w1t + (size_t)e * ((size_t)I_DIM * H_DIM) + (size_t)n0 * H_DIM;

  // staging: LDS dest linear; source chunk pre-swizzled: cg = (lane&7)^(row&7)
  const int srow = lane >> 3;
  const int cg = (lane & 7) ^ srow;
  const char* aptr[4];
  const char* bptr[4];
#pragma unroll
  for (int i = 0; i < 4; ++i) {
    const int r = i * 32 + wid * 8 + srow;
    const int rr = (r < cnt_local) ? r : (cnt_local - 1);
    const int tok = rowmap[off_e + loc_rt * BM + rr] >> 1;
    aptr[i] = (const char*)(hsb + (size_t)tok * H_DIM) + cg * 16;
    bptr[i] = (const char*)(wbase + (size_t)r * H_DIM) + cg * 16;
  }
  unsigned short* dstA[4];
  unsigned short* dstB[4];
#pragma unroll
  for (int i = 0; i < 4; ++i) {
    dstA[i] = &As[(i * 32 + wid * 8) * BK];   // wave-uniform
    dstB[i] = &Bs[(i * 32 + wid * 8) * BK];
  }

  f32x4 acc[4][4];
#pragma unroll
  for (int m = 0; m < 4; ++m)
#pragma unroll
    for (int n = 0; n < 4; ++n) acc[m][n] = (f32x4){0.f, 0.f, 0.f, 0.f};

  const int wm = (wid >> 1) * 64;
  const int wn = (wid & 1) * 64;
  const int fr = lane & 15;
  const int fq = lane >> 4;
  const int sxor = fr & 7;

  for (int k0 = 0; k0 < H_DIM; k0 += BK) {
    const int kb = k0 * 2;
#pragma unroll
    for (int i = 0; i < 4; ++i) gload16(aptr[i] + kb, dstA[i]);
#pragma unroll
    for (int i = 0; i < 4; ++i) gload16(bptr[i] + kb, dstB[i]);
    __syncthreads();   // drains vmcnt before s_barrier

#pragma unroll
    for (int kk = 0; kk < 2; ++kk) {
      bf16x8 af[4], bf[4];
#pragma unroll
      for (int m = 0; m < 4; ++m)
        af[m] = *reinterpret_cast<const bf16x8*>(
            &As[(wm + m * 16 + fr) * BK + ((kk * 4 + fq) ^ sxor) * 8]);
#pragma unroll
      for (int n = 0; n < 4; ++n)
        bf[n] = *reinterpret_cast<const bf16x8*>(
            &Bs[(wn + n * 16 + fr) * BK + ((kk * 4 + fq) ^ sxor) * 8]);
#pragma unroll
      for (int m = 0; m < 4; ++m)
#pragma unroll
        for (int n = 0; n < 4; ++n)
          acc[m][n] = __builtin_amdgcn_mfma_f32_16x16x32_bf16(af[m], bf[n], acc[m][n], 0, 0, 0);
    }
    __syncthreads();
  }

  // ---- epilogue: silu -> act bf16
#pragma unroll
  for (int m = 0; m < 4; ++m) {
    const int row = wm + m * 16 + fq * 4;
#pragma unroll
    for (int n = 0; n < 4; ++n) {
      const int col = wn + n * 16 + fr;
#pragma unroll
      for (int r = 0; r < 4; ++r) {
        const int rw = row + r;
        if (rw < cnt_local) {
          const float x = acc[m][n][r];
          const float s = x / (1.f + __expf(-x));
          act[(size_t)(r_base + rw) * I_DIM + n0 + col] = f2bf(s);
        }
      }
    }
  }
}

// ---------------- gemm1 (128x128, band-of-2rt chunks, plain res stores) ----
__launch_bounds__(256, 4)
__global__ void moe_gemm1(const unsigned short* __restrict__ w2t,
                          const unsigned short* __restrict__ act_in,
                          float* __restrict__ res,
                          const int* __restrict__ counts,
                          const int* __restrict__ rowmap,
                          const float* __restrict__ wgt) {
  constexpr int NCT = H_DIM / BN;            // 8
  constexpr int NWG = MAX_RT * NCT;          // 576
  constexpr int CHUNK = NWG / 8;             // 72

  __shared__ unsigned short As[BM * BK];
  __shared__ unsigned short Bs[BN * BK];
  __shared__ float s_w[BM];

  // T1 bijective XCD swizzle; band of 2rt x 8ct within each 72-wgid chunk
  const int bid = blockIdx.x;
  const int wgid = (bid & 7) * CHUNK + (bid >> 3);
  int rt, ct;
  {
    const int c9 = (wgid / CHUNK) * 9;
    const int l = wgid % CHUNK;
    if (l < 64) {
      const int band = l >> 4, inner = l & 15;
      rt = c9 + band * 2 + (inner & 1);
      ct = inner >> 1;
    } else {
      rt = c9 + 8;
      ct = l - 64;
    }
  }

  // expert walk from counts (prefix on the fly)
  int e = -1, loc_rt = 0, off_e = 0, cnt = 0;
  {
    int acc_t = 0, off = 0;
#pragma unroll
    for (int ee = 0; ee < E_NUM; ++ee) {
      const int c = counts[ee];
      const int nt = (c + BM - 1) >> 7;
      if (e < 0 && rt < acc_t + nt) { e = ee; loc_rt = rt - acc_t; off_e = off; cnt = c; }
      acc_t += nt; off += c;
    }
  }
  if (e < 0) return;

  const int cnt_local = min(BM, cnt - loc_rt * BM);
  const int r_base = off_e + loc_rt * BM;
  const int th = threadIdx.x;
  const int lane = th & 63, wid = th >> 6;

  if (th < BM) {
    int r = loc_rt * BM + th;
    if (r >= cnt) r = cnt - 1;
    s_w[th] = wgt[rowmap[off_e + r]];
  }

  const int n0 = ct * BN;
  const unsigned short* wbase = w2t + (size_t)e * ((size_t)I_DIM * H_DIM) + (size_t)n0 * I_DIM;

  const int srow = lane >> 3;
  const int cg = (lane & 7) ^ srow;
  const char* aptr[4];
  const char* bptr[4];
#pragma unroll
  for (int i = 0; i < 4; ++i) {
    const int r = i * 32 + wid * 8 + srow;
    const int rr = (r < cnt_local) ? r : (cnt_local - 1);
    aptr[i] = (const char*)(act_in + (size_t)(r_base + rr) * I_DIM) + cg * 16;
    bptr[i] = (const char*)(wbase + (size_t)r * I_DIM) + cg * 16;
  }
  unsigned short* dstA[4];
  unsigned short* dstB[4];
#pragma unroll
  for (int i = 0; i < 4; ++i) {
    dstA[i] = &As[(i * 32 + wid * 8) * BK];
    dstB[i] = &Bs[(i * 32 + wid * 8) * BK];
  }

  f32x4 acc[4][4];
#pragma unroll
  for (int m = 0; m < 4; ++m)
#pragma unroll
    for (int n = 0; n < 4; ++n) acc[m][n] = (f32x4){0.f, 0.f, 0.f, 0.f};

  const int wm = (wid >> 1) * 64;
  const int wn = (wid & 1) * 64;
  const int fr = lane & 15;
  const int fq = lane >> 4;
  const int sxor = fr & 7;

  for (int k0 = 0; k0 < I_DIM; k0 += BK) {
    const int kb = k0 * 2;
#pragma unroll
    for (int i = 0; i < 4; ++i) gload16(aptr[i] + kb, dstA[i]);
#pragma unroll
    for (int i = 0; i < 4; ++i) gload16(bptr[i] + kb, dstB[i]);
    __syncthreads();

#pragma unroll
    for (int kk = 0; kk < 2; ++kk) {
      bf16x8 af[4], bf[4];
#pragma unroll
      for (int m = 0; m < 4; ++m)
        af[m] = *reinterpret_cast<const bf16x8*>(
            &As[(wm + m * 16 + fr) * BK + ((kk * 4 + fq) ^ sxor) * 8]);
#pragma unroll
      for (int n = 0; n < 4; ++n)
        bf[n] = *reinterpret_cast<const bf16x8*>(
            &Bs[(wn + n * 16 + fr) * BK + ((kk * 4 + fq) ^ sxor) * 8]);
#pragma unroll
      for (int m = 0; m < 4; ++m)
#pragma unroll
        for (int n = 0; n < 4; ++n)
          acc[m][n] = __builtin_amdgcn_mfma_f32_16x16x32_bf16(af[m], bf[n], acc[m][n], 0, 0, 0);
    }
    __syncthreads();
  }

#pragma unroll
  for (int m = 0; m < 4; ++m) {
    const int row = wm + m * 16 + fq * 4;
#pragma unroll
    for (int n = 0; n < 4; ++n) {
      const int col = wn + n * 16 + fr;
#pragma unroll
      for (int r = 0; r < 4; ++r) {
        const int rw = row + r;
        if (rw < cnt_local)
          res[(size_t)(r_base + rw) * H_DIM + n0 + col] = acc[m][n][r] * s_w[rw];
      }
    }
  }
}

// ---------------- launch ----------------
extern "C" void kernel_launch(void* const* d_in, const int* in_sizes, int n_in,
                              void* d_out, int out_size, void* d_ws, size_t ws_size,
                              hipStream_t stream) {
  const float* hs = (const float*)d_in[0];
  const float* gw = (const float*)d_in[1];
  const float* w1 = (const float*)d_in[2];
  const float* w2 = (const float*)d_in[3];
  float* out = (float*)d_out;

  char* ws = (char*)d_ws;
  const size_t WMAT = (size_t)E_NUM * I_DIM * H_DIM * 2;   // 58,720,256 B
  unsigned short* w1t = (unsigned short*)ws;                // [E][I][H] bf16
  unsigned short* w2t = (unsigned short*)(ws + WMAT);       // [E][H][I] bf16
  unsigned short* act = (unsigned short*)(ws + 2 * WMAT);   // [NPAIR][I] bf16
  unsigned short* hsb = (unsigned short*)(ws + 3 * WMAT);   // [T][H] bf16
  // res aliases w1t: dead after gemm0_w2t completes (stream-ordered).
  float* res = (float*)w1t;                                 // [NPAIR][H] fp32
  char* small = ws + 3 * WMAT + (size_t)T_TOK * H_DIM * 2;
  int* eid = (int*)small;                          // NPAIR
  float* wgt = (float*)(small + NPAIR * 4);        // NPAIR
  int* rowmap = (int*)(small + 2 * NPAIR * 4);     // NPAIR
  int* posmap = (int*)(small + 3 * NPAIR * 4);     // NPAIR
  int* counts = (int*)(small + 4 * NPAIR * 4);     // 8
  int* fill = counts + 8;                          // 8

  hipMemsetAsync(counts, 0, 16 * sizeof(int), stream);

  prep1_kernel<<<256 + WT_NB, 256, 0, stream>>>(w1, hs, gw, w1t, hsb, eid, wgt, counts);
  scatter_kernel<<<NPAIR / 256, 256, 0, stream>>>(eid, counts, fill, rowmap, posmap);

  gemm0_w2t_kernel<<<G0_NWG + WT_NB, 256, 0, stream>>>(
      hsb, w1t, act, w2, w2t, counts, rowmap);
  moe_gemm1<<<MAX_RT * (H_DIM / BN), 256, 0, stream>>>(
      w2t, act, res, counts, rowmap, wgt);

  combine_kernel<<<T_TOK, 256, 0, stream>>>(res, posmap, out);
}